// Round 1
// baseline (1419.618 us; speedup 1.0000x reference)
//
#include <hip/hip_runtime.h>
#include <math.h>

#define N_NODES 50000
#define N_EDGES 800000
#define DIN 128

// ---------------------------------------------------------------------------
// Tiled fp32 GEMM (no fp32 MFMA on CDNA4 -> VALU).
// C[M x N] = A1[M x 128] @ B1[128 x N] (+ A2[M x 128] @ B2[128 x N]) + bias[N]
// 64x64 tile, 256 threads, 4x4 per thread. LDS rows padded to 68 floats
// (272 B = 17 * 16 B, keeps float4-aligned LDS reads).
// ---------------------------------------------------------------------------
template <bool DUAL>
__global__ __launch_bounds__(256) void gemm_k128(
    const float* __restrict__ A1, const float* __restrict__ B1,
    const float* __restrict__ A2, const float* __restrict__ B2,
    const float* __restrict__ bias, float* __restrict__ C,
    int M, int N)
{
    const int K = 128;
    __shared__ float As[32][68];
    __shared__ float Bs[32][68];

    const int tid = threadIdx.x;
    const int tx = tid & 15;   // col group 0..15
    const int ty = tid >> 4;   // row group 0..15
    const int rowBase = blockIdx.y * 64;
    const int colBase = blockIdx.x * 64;

    float acc[4][4] = {};

    const int phases = DUAL ? 2 : 1;
    for (int ph = 0; ph < phases; ++ph) {
        const float* __restrict__ A = (ph == 0) ? A1 : A2;
        const float* __restrict__ B = (ph == 0) ? B1 : B2;
        for (int kk = 0; kk < K; kk += 32) {
            // A tile: 64 rows x 32 k  -> As[k][m] (transposed into LDS)
            #pragma unroll
            for (int i = 0; i < 8; ++i) {
                int t = tid + i * 256;        // 0..2047
                int m = t >> 5;
                int k = t & 31;
                int row = rowBase + m;
                As[k][m] = (row < M) ? A[row * K + kk + k] : 0.0f;
            }
            // B tile: 32 k x 64 cols -> Bs[k][n]
            #pragma unroll
            for (int i = 0; i < 8; ++i) {
                int t = tid + i * 256;
                int k = t >> 6;
                int n = t & 63;
                Bs[k][n] = B[(kk + k) * N + colBase + n]; // N multiple of 64
            }
            __syncthreads();
            #pragma unroll
            for (int k = 0; k < 32; ++k) {
                float a[4], b[4];
                #pragma unroll
                for (int i = 0; i < 4; ++i) a[i] = As[k][ty * 4 + i];
                #pragma unroll
                for (int j = 0; j < 4; ++j) b[j] = Bs[k][tx * 4 + j];
                #pragma unroll
                for (int i = 0; i < 4; ++i)
                    #pragma unroll
                    for (int j = 0; j < 4; ++j)
                        acc[i][j] += a[i] * b[j];
            }
            __syncthreads();
        }
    }

    #pragma unroll
    for (int i = 0; i < 4; ++i) {
        int row = rowBase + ty * 4 + i;
        if (row >= M) continue;
        #pragma unroll
        for (int j = 0; j < 4; ++j) {
            int col = colBase + tx * 4 + j;
            C[row * N + col] = acc[i][j] + bias[col];
        }
    }
}

// ---------------------------------------------------------------------------
// Edge scatter-max: pool[dst[e]][d] = max over edges of relu(y[src[e]][d]).
// pool pre-zeroed; relu'd values are >= 0 so unsigned-bit atomicMax == float
// max, and zero-degree nodes stay 0 (matches the reference's where(deg>0)).
// Skip atomics for v == 0 (pool already 0).
// ---------------------------------------------------------------------------
__global__ __launch_bounds__(256) void scatter_max(
    const float* __restrict__ y,
    const int* __restrict__ src,
    const int* __restrict__ dst,
    unsigned int* __restrict__ pool)
{
    unsigned int idx = blockIdx.x * 256u + threadIdx.x;   // < E*128 = 102.4M
    int e = idx >> 7;
    int d = idx & 127;
    int s = src[e];           // wave-uniform (128 dims/edge, 64 lanes/wave)
    float v = y[s * DIN + d];
    v = fmaxf(v, 0.0f);
    if (v > 0.0f) {
        int t = dst[e];
        atomicMax(&pool[t * DIN + d], __float_as_uint(v));
    }
}

// ---------------------------------------------------------------------------
// Row-wise L2 normalize + relu. One block per node, D threads (D = 64 or 128).
// Safe in-place (each element read into a register before any cross-thread
// dependency).
// ---------------------------------------------------------------------------
template <int D>
__global__ __launch_bounds__(D) void l2norm_relu(
    const float* __restrict__ in, float* __restrict__ out)
{
    int n = blockIdx.x;
    int d = threadIdx.x;
    float v = in[n * D + d];
    float s = v * v;
    #pragma unroll
    for (int off = 32; off > 0; off >>= 1) s += __shfl_xor(s, off, 64);
    float total;
    if (D == 128) {
        __shared__ float ws_[2];
        if ((d & 63) == 0) ws_[d >> 6] = s;
        __syncthreads();
        total = ws_[0] + ws_[1];
    } else {
        total = s;
    }
    float norm = sqrtf(total);
    float r = v / fmaxf(norm, 1e-12f);
    out[n * D + d] = fmaxf(r, 0.0f);
}

extern "C" void kernel_launch(void* const* d_in, const int* in_sizes, int n_in,
                              void* d_out, int out_size, void* d_ws, size_t ws_size,
                              hipStream_t stream) {
    const float* x    = (const float*)d_in[0];
    const int*   esrc = (const int*)d_in[1];
    const int*   edst = (const int*)d_in[2];
    // per layer l (0..2): Wp=d_in[3+5l], bp=4+5l, Ws=5+5l, Wn=6+5l, b=7+5l
    const float* Wp[3], *bp[3], *Ws[3], *Wn[3], *bb[3];
    for (int l = 0; l < 3; ++l) {
        Wp[l] = (const float*)d_in[3 + 5 * l];
        bp[l] = (const float*)d_in[4 + 5 * l];
        Ws[l] = (const float*)d_in[5 + 5 * l];
        Wn[l] = (const float*)d_in[6 + 5 * l];
        bb[l] = (const float*)d_in[7 + 5 * l];
    }

    const size_t NODE_FEAT = (size_t)N_NODES * DIN;           // 6.4M floats
    float* P0 = (float*)d_ws;
    float* P1 = P0 + NODE_FEAT;   // pool buffer
    float* P2 = P1 + NODE_FEAT;

    const dim3 blk(256);
    const dim3 gemmGrid128(2, (N_NODES + 63) / 64);   // N=128
    const dim3 gemmGrid64(1, (N_NODES + 63) / 64);    // N=64
    const int scatterBlocks = (N_EDGES * DIN) / 256;  // 400000

    // ---- Layer 1: in = x, out(h1) = P2 ----
    gemm_k128<false><<<gemmGrid128, blk, 0, stream>>>(x, Wp[0], nullptr, nullptr, bp[0], P0, N_NODES, 128);
    hipMemsetAsync(P1, 0, NODE_FEAT * sizeof(float), stream);
    scatter_max<<<scatterBlocks, blk, 0, stream>>>(P0, esrc, edst, (unsigned int*)P1);
    gemm_k128<true><<<gemmGrid128, blk, 0, stream>>>(x, Ws[0], P1, Wn[0], bb[0], P2, N_NODES, 128);
    l2norm_relu<128><<<N_NODES, 128, 0, stream>>>(P2, P2);

    // ---- Layer 2: in = P2, out(h2) = P0 ----
    gemm_k128<false><<<gemmGrid128, blk, 0, stream>>>(P2, Wp[1], nullptr, nullptr, bp[1], P0, N_NODES, 128);
    hipMemsetAsync(P1, 0, NODE_FEAT * sizeof(float), stream);
    scatter_max<<<scatterBlocks, blk, 0, stream>>>(P0, esrc, edst, (unsigned int*)P1);
    gemm_k128<true><<<gemmGrid128, blk, 0, stream>>>(P2, Ws[1], P1, Wn[1], bb[1], P0, N_NODES, 128);
    l2norm_relu<128><<<N_NODES, 128, 0, stream>>>(P0, P0);

    // ---- Layer 3: in = P0, out -> d_out (dout = 64) ----
    gemm_k128<false><<<gemmGrid128, blk, 0, stream>>>(P0, Wp[2], nullptr, nullptr, bp[2], P2, N_NODES, 128);
    hipMemsetAsync(P1, 0, NODE_FEAT * sizeof(float), stream);
    scatter_max<<<scatterBlocks, blk, 0, stream>>>(P2, esrc, edst, (unsigned int*)P1);
    gemm_k128<true><<<gemmGrid64, blk, 0, stream>>>(P0, Ws[2], P1, Wn[2], bb[2], P2, N_NODES, 64);
    l2norm_relu<64><<<N_NODES, 64, 0, stream>>>(P2, (float*)d_out);
}

// Round 2
// 702.502 us; speedup vs baseline: 2.0208x; 2.0208x over previous
//
#include <hip/hip_runtime.h>
#include <math.h>

#define N_NODES 50000
#define N_EDGES 800000
#define DIN 128

// ---------------------------------------------------------------------------
// Tiled fp32 GEMM (no fp32 MFMA on CDNA4 -> VALU).
// C[M x N] = A1[M x 128] @ B1[128 x N] (+ A2[M x 128] @ B2[128 x N]) + bias[N]
// 64x64 tile, 256 threads, 4x4 per thread. LDS rows padded to 68 floats.
// ---------------------------------------------------------------------------
template <bool DUAL>
__global__ __launch_bounds__(256) void gemm_k128(
    const float* __restrict__ A1, const float* __restrict__ B1,
    const float* __restrict__ A2, const float* __restrict__ B2,
    const float* __restrict__ bias, float* __restrict__ C,
    int M, int N)
{
    const int K = 128;
    __shared__ float As[32][68];
    __shared__ float Bs[32][68];

    const int tid = threadIdx.x;
    const int tx = tid & 15;
    const int ty = tid >> 4;
    const int rowBase = blockIdx.y * 64;
    const int colBase = blockIdx.x * 64;

    float acc[4][4] = {};

    const int phases = DUAL ? 2 : 1;
    for (int ph = 0; ph < phases; ++ph) {
        const float* __restrict__ A = (ph == 0) ? A1 : A2;
        const float* __restrict__ B = (ph == 0) ? B1 : B2;
        for (int kk = 0; kk < K; kk += 32) {
            #pragma unroll
            for (int i = 0; i < 8; ++i) {
                int t = tid + i * 256;
                int m = t >> 5;
                int k = t & 31;
                int row = rowBase + m;
                As[k][m] = (row < M) ? A[row * K + kk + k] : 0.0f;
            }
            #pragma unroll
            for (int i = 0; i < 8; ++i) {
                int t = tid + i * 256;
                int k = t >> 6;
                int n = t & 63;
                Bs[k][n] = B[(kk + k) * N + colBase + n];
            }
            __syncthreads();
            #pragma unroll
            for (int k = 0; k < 32; ++k) {
                float a[4], b[4];
                #pragma unroll
                for (int i = 0; i < 4; ++i) a[i] = As[k][ty * 4 + i];
                #pragma unroll
                for (int j = 0; j < 4; ++j) b[j] = Bs[k][tx * 4 + j];
                #pragma unroll
                for (int i = 0; i < 4; ++i)
                    #pragma unroll
                    for (int j = 0; j < 4; ++j)
                        acc[i][j] += a[i] * b[j];
            }
            __syncthreads();
        }
    }

    #pragma unroll
    for (int i = 0; i < 4; ++i) {
        int row = rowBase + ty * 4 + i;
        if (row >= M) continue;
        #pragma unroll
        for (int j = 0; j < 4; ++j) {
            int col = colBase + tx * 4 + j;
            C[row * N + col] = acc[i][j] + bias[col];
        }
    }
}

// ---------------------------------------------------------------------------
// CSR build: histogram of dst, exclusive scan, position-claim fill.
// ---------------------------------------------------------------------------
__global__ __launch_bounds__(256) void edge_histogram(
    const int* __restrict__ dst, int* __restrict__ deg)
{
    int e = blockIdx.x * 256 + threadIdx.x;
    if (e < N_EDGES) atomicAdd(&deg[dst[e]], 1);
}

// Pass A: per-block partial sums of deg (50001 entries, 196 blocks).
__global__ __launch_bounds__(256) void scan_partial(
    const int* __restrict__ deg, int* __restrict__ partials)
{
    __shared__ int sm[256];
    int i = blockIdx.x * 256 + threadIdx.x;
    int v = (i <= N_NODES) ? deg[i] : 0;
    sm[threadIdx.x] = v;
    __syncthreads();
    for (int off = 128; off > 0; off >>= 1) {
        if (threadIdx.x < off) sm[threadIdx.x] += sm[threadIdx.x + off];
        __syncthreads();
    }
    if (threadIdx.x == 0) partials[blockIdx.x] = sm[0];
}

// Pass B: serial exclusive scan of 196 partials (trivial).
__global__ void scan_base(int* __restrict__ partials, int nb)
{
    int base = 0;
    for (int b = 0; b < nb; ++b) {
        int t = partials[b];
        partials[b] = base;
        base += t;
    }
}

// Pass C: intra-block Hillis-Steele exclusive scan + block base -> offs.
__global__ __launch_bounds__(256) void scan_write(
    const int* __restrict__ deg, const int* __restrict__ partials,
    int* __restrict__ offs)
{
    __shared__ int sm[256];
    int i = blockIdx.x * 256 + threadIdx.x;
    int t = threadIdx.x;
    int v = (i <= N_NODES) ? deg[i] : 0;
    sm[t] = v;
    __syncthreads();
    for (int off = 1; off < 256; off <<= 1) {
        int add = (t >= off) ? sm[t - off] : 0;
        __syncthreads();
        sm[t] += add;
        __syncthreads();
    }
    if (i <= N_NODES) offs[i] = partials[blockIdx.x] + sm[t] - v;
}

__global__ __launch_bounds__(256) void csr_fill(
    const int* __restrict__ src, const int* __restrict__ dst,
    const int* __restrict__ offs, int* __restrict__ cursor,
    int* __restrict__ csr_src)
{
    int e = blockIdx.x * 256 + threadIdx.x;
    if (e < N_EDGES) {
        int dn = dst[e];
        int p = atomicAdd(&cursor[dn], 1);
        csr_src[offs[dn] + p] = src[e];
    }
}

// ---------------------------------------------------------------------------
// Gather max-pool: one wave per node; lane d handles dims {2d, 2d+1}.
// acc=0 init realizes both the relu-before-max identity and zero-degree->0.
// No atomics, one coalesced 512B write per node, deterministic.
// ---------------------------------------------------------------------------
__global__ __launch_bounds__(64) void pool_max(
    const float* __restrict__ y, const int* __restrict__ offs,
    const int* __restrict__ csr_src, float* __restrict__ pool)
{
    int n = blockIdx.x;
    int d = threadIdx.x;            // 0..63
    int e0 = offs[n], e1 = offs[n + 1];
    float2 acc = make_float2(0.0f, 0.0f);
    int e = e0;
    for (; e + 1 < e1; e += 2) {
        int s0 = csr_src[e];
        int s1 = csr_src[e + 1];
        float2 v0 = *(const float2*)&y[s0 * DIN + 2 * d];
        float2 v1 = *(const float2*)&y[s1 * DIN + 2 * d];
        acc.x = fmaxf(acc.x, v0.x); acc.y = fmaxf(acc.y, v0.y);
        acc.x = fmaxf(acc.x, v1.x); acc.y = fmaxf(acc.y, v1.y);
    }
    if (e < e1) {
        int s0 = csr_src[e];
        float2 v0 = *(const float2*)&y[s0 * DIN + 2 * d];
        acc.x = fmaxf(acc.x, v0.x); acc.y = fmaxf(acc.y, v0.y);
    }
    *(float2*)&pool[n * DIN + 2 * d] = acc;
}

// ---------------------------------------------------------------------------
// Row-wise L2 normalize + relu.
// ---------------------------------------------------------------------------
template <int D>
__global__ __launch_bounds__(D) void l2norm_relu(
    const float* __restrict__ in, float* __restrict__ out)
{
    int n = blockIdx.x;
    int d = threadIdx.x;
    float v = in[n * D + d];
    float s = v * v;
    #pragma unroll
    for (int off = 32; off > 0; off >>= 1) s += __shfl_xor(s, off, 64);
    float total;
    if (D == 128) {
        __shared__ float ws_[2];
        if ((d & 63) == 0) ws_[d >> 6] = s;
        __syncthreads();
        total = ws_[0] + ws_[1];
    } else {
        total = s;
    }
    float norm = sqrtf(total);
    float r = v / fmaxf(norm, 1e-12f);
    out[n * D + d] = fmaxf(r, 0.0f);
}

extern "C" void kernel_launch(void* const* d_in, const int* in_sizes, int n_in,
                              void* d_out, int out_size, void* d_ws, size_t ws_size,
                              hipStream_t stream) {
    const float* x    = (const float*)d_in[0];
    const int*   esrc = (const int*)d_in[1];
    const int*   edst = (const int*)d_in[2];
    const float* Wp[3], *bp[3], *Ws[3], *Wn[3], *bb[3];
    for (int l = 0; l < 3; ++l) {
        Wp[l] = (const float*)d_in[3 + 5 * l];
        bp[l] = (const float*)d_in[4 + 5 * l];
        Ws[l] = (const float*)d_in[5 + 5 * l];
        Wn[l] = (const float*)d_in[6 + 5 * l];
        bb[l] = (const float*)d_in[7 + 5 * l];
    }

    const size_t NODE_FEAT = (size_t)N_NODES * DIN;   // 6.4M floats, 25.6 MB
    float* P0 = (float*)d_ws;
    float* P1 = P0 + NODE_FEAT;
    float* P2 = P1 + NODE_FEAT;
    int*   deg      = (int*)(P2 + NODE_FEAT);         // 50001
    int*   offs     = deg + (N_NODES + 1);            // 50001
    int*   cursor   = offs + (N_NODES + 1);           // 50000
    int*   partials = cursor + N_NODES;               // 256
    int*   csr_src  = partials + 256;                 // 800000

    const dim3 blk(256);
    const dim3 gemmGrid128(2, (N_NODES + 63) / 64);
    const dim3 gemmGrid64(1, (N_NODES + 63) / 64);
    const int edgeBlocks = (N_EDGES + 255) / 256;          // 3125
    const int scanBlocks = (N_NODES + 1 + 255) / 256;      // 196

    // ---- CSR build (once; graph identical for all 3 layers) ----
    hipMemsetAsync(deg, 0, (2 * (N_NODES + 1) + N_NODES + 256) * sizeof(int), stream);
    edge_histogram<<<edgeBlocks, blk, 0, stream>>>(edst, deg);
    scan_partial<<<scanBlocks, blk, 0, stream>>>(deg, partials);
    scan_base<<<1, 1, 0, stream>>>(partials, scanBlocks);
    scan_write<<<scanBlocks, blk, 0, stream>>>(deg, partials, offs);
    csr_fill<<<edgeBlocks, blk, 0, stream>>>(esrc, edst, offs, cursor, csr_src);

    // ---- Layer 1: in = x -> h1 = P2 ----
    gemm_k128<false><<<gemmGrid128, blk, 0, stream>>>(x, Wp[0], nullptr, nullptr, bp[0], P0, N_NODES, 128);
    pool_max<<<N_NODES, 64, 0, stream>>>(P0, offs, csr_src, P1);
    gemm_k128<true><<<gemmGrid128, blk, 0, stream>>>(x, Ws[0], P1, Wn[0], bb[0], P2, N_NODES, 128);
    l2norm_relu<128><<<N_NODES, 128, 0, stream>>>(P2, P2);

    // ---- Layer 2: in = P2 -> h2 = P0 ----
    gemm_k128<false><<<gemmGrid128, blk, 0, stream>>>(P2, Wp[1], nullptr, nullptr, bp[1], P0, N_NODES, 128);
    pool_max<<<N_NODES, 64, 0, stream>>>(P0, offs, csr_src, P1);
    gemm_k128<true><<<gemmGrid128, blk, 0, stream>>>(P2, Ws[1], P1, Wn[1], bb[1], P0, N_NODES, 128);
    l2norm_relu<128><<<N_NODES, 128, 0, stream>>>(P0, P0);

    // ---- Layer 3: in = P0 -> d_out (dout = 64) ----
    gemm_k128<false><<<gemmGrid128, blk, 0, stream>>>(P0, Wp[2], nullptr, nullptr, bp[2], P2, N_NODES, 128);
    pool_max<<<N_NODES, 64, 0, stream>>>(P2, offs, csr_src, P1);
    gemm_k128<true><<<gemmGrid64, blk, 0, stream>>>(P0, Ws[2], P1, Wn[2], bb[2], P2, N_NODES, 64);
    l2norm_relu<64><<<N_NODES, 64, 0, stream>>>(P2, (float*)d_out);
}

// Round 3
// 473.133 us; speedup vs baseline: 3.0005x; 1.4848x over previous
//
#include <hip/hip_runtime.h>
#include <math.h>

#define N_NODES 50000
#define N_EDGES 800000
#define DIN 128

typedef __attribute__((ext_vector_type(8))) short short8;   // 8 bf16
typedef __attribute__((ext_vector_type(4))) float f32x4;    // 4 fp32 acc

// ---------------- bf16 helpers (RNE) ----------------
__device__ __forceinline__ unsigned short f2bf(float f) {
    unsigned int u = __float_as_uint(f);
    return (unsigned short)((u + 0x7FFFu + ((u >> 16) & 1u)) >> 16);
}
__device__ __forceinline__ float bf2f(unsigned short h) {
    return __uint_as_float(((unsigned int)h) << 16);
}

// ---------------------------------------------------------------------------
// MFMA GEMM, 16x16x32 bf16. Block = 256 thr = 4 waves; each wave owns 16 rows
// x N cols (NTILES tiles of 16). A: row-major bf16 [M][128] planes, loaded
// straight from global (16B/lane). B: pre-packed fragment layout
// Bp[c][n][q][j] = W[c*32+q*8+j][n] -> wave-contiguous 1KB loads, L1-resident.
// Segments realize the fp32 hi/lo split: acc = sum_s A_s @ B_s.
// Fragment layouts (m89/m120-verified):
//   A: lane holds A[m=lane&15][k=quad*8+j]   (quad = lane>>4, j = 0..7)
//   B: lane holds B[k=quad*8+j][n=lane&15]
//   D: lane reg g holds D[row=quad*4+g][col=lane&15]
// OMODE 0: out = acc+bias -> bf16 raw (y for pooling)
// OMODE 1: l2norm+relu -> bf16 hi/lo planes (next layer's A)
// OMODE 2: l2norm+relu -> fp32 (final output)
// ---------------------------------------------------------------------------
struct GSegs { const unsigned short* a[4]; const unsigned short* b[4]; };

template <int NTILES, int NSEG, int OMODE>
__global__ __launch_bounds__(256) void gemm_mfma(
    GSegs segs, const float* __restrict__ bias,
    unsigned short* __restrict__ outH, unsigned short* __restrict__ outL,
    float* __restrict__ outF, int M)
{
    const int N = NTILES * 16;
    const int lane = threadIdx.x & 63;
    const int wv = threadIdx.x >> 6;
    const int cl = lane & 15;
    const int quad = lane >> 4;
    const int rowBase = blockIdx.x * 64 + wv * 16;

    f32x4 acc[NTILES];
    #pragma unroll
    for (int t = 0; t < NTILES; ++t) acc[t] = (f32x4){0.f, 0.f, 0.f, 0.f};

    const int aBase = (rowBase + cl) * 128 + quad * 8;
    const int bLane = cl * 32 + quad * 8;

    #pragma unroll
    for (int s = 0; s < NSEG; ++s) {
        const unsigned short* __restrict__ A = segs.a[s];
        const unsigned short* __restrict__ B = segs.b[s];
        #pragma unroll
        for (int c = 0; c < 4; ++c) {
            short8 af = *(const short8*)(A + aBase + c * 32);
            const unsigned short* Bc = B + c * (N * 32) + bLane;
            #pragma unroll
            for (int t = 0; t < NTILES; ++t) {
                short8 bf = *(const short8*)(Bc + t * 512);
                acc[t] = __builtin_amdgcn_mfma_f32_16x16x32_bf16(af, bf, acc[t], 0, 0, 0);
            }
        }
    }

    // bias (before l2norm, matching reference)
    #pragma unroll
    for (int t = 0; t < NTILES; ++t) {
        float bc = bias[t * 16 + cl];
        #pragma unroll
        for (int g = 0; g < 4; ++g) acc[t][g] += bc;
    }

    const int row0 = rowBase + quad * 4;

    if (OMODE == 0) {
        #pragma unroll
        for (int t = 0; t < NTILES; ++t)
            #pragma unroll
            for (int g = 0; g < 4; ++g) {
                int r = row0 + g;
                if (r < M) outH[r * N + t * 16 + cl] = f2bf(acc[t][g]);
            }
        return;
    }

    // fused row-wise L2 norm: row lives in the 16 lanes of this quad group
    float inv[4];
    #pragma unroll
    for (int g = 0; g < 4; ++g) {
        float s = 0.f;
        #pragma unroll
        for (int t = 0; t < NTILES; ++t) s += acc[t][g] * acc[t][g];
        s += __shfl_xor(s, 1, 64);
        s += __shfl_xor(s, 2, 64);
        s += __shfl_xor(s, 4, 64);
        s += __shfl_xor(s, 8, 64);
        inv[g] = 1.0f / fmaxf(sqrtf(s), 1e-12f);
    }

    #pragma unroll
    for (int t = 0; t < NTILES; ++t)
        #pragma unroll
        for (int g = 0; g < 4; ++g) {
            int r = row0 + g;
            if (r >= M) continue;
            float o = fmaxf(acc[t][g] * inv[g], 0.0f);
            int off = r * N + t * 16 + cl;
            if (OMODE == 1) {
                unsigned short h = f2bf(o);
                outH[off] = h;
                outL[off] = f2bf(o - bf2f(h));
            } else {
                outF[off] = o;
            }
        }
}

// ---------------------------------------------------------------------------
// Weight pre-pack: W[K x N] fp32 -> Bp_hi/Bp_lo in fragment layout
// Bp[((c*N + n)*4 + q)*8 + j] = W[(c*32 + q*8 + j)*N + n].  id maps directly:
// c = id/(N*32), n = (id/32)%N, k = c*32 + (id&31).
// ---------------------------------------------------------------------------
struct WDesc { const float* W; int N; };
struct WDescs { WDesc d[9]; };

__global__ __launch_bounds__(256) void convert_weights(WDescs wd, unsigned short* base)
{
    int mi = blockIdx.y;
    int id = blockIdx.x * 256 + threadIdx.x;
    const float* W = wd.d[mi].W;
    int N = wd.d[mi].N;
    if (id >= 128 * N) return;
    int c = id / (N * 32);
    int n = (id - c * N * 32) >> 5;
    int k = c * 32 + (id & 31);
    float v = W[k * N + n];
    unsigned short h = f2bf(v);
    unsigned short* hi = base + mi * 32768;
    hi[id] = h;
    hi[16384 + id] = f2bf(v - bf2f(h));
}

// x fp32 -> hi/lo bf16 planes (2 elements per thread)
__global__ __launch_bounds__(256) void convert_x(
    const float* __restrict__ x, unsigned short* __restrict__ xh,
    unsigned short* __restrict__ xl)
{
    int i = blockIdx.x * 256 + threadIdx.x;
    float2 v = ((const float2*)x)[i];
    ushort2 h, l;
    h.x = f2bf(v.x); l.x = f2bf(v.x - bf2f(h.x));
    h.y = f2bf(v.y); l.y = f2bf(v.y - bf2f(h.y));
    ((ushort2*)xh)[i] = h;
    ((ushort2*)xl)[i] = l;
}

// ---------------------------------------------------------------------------
// CSR build (unchanged from round 2)
// ---------------------------------------------------------------------------
__global__ __launch_bounds__(256) void edge_histogram(
    const int* __restrict__ dst, int* __restrict__ deg)
{
    int e = blockIdx.x * 256 + threadIdx.x;
    if (e < N_EDGES) atomicAdd(&deg[dst[e]], 1);
}

__global__ __launch_bounds__(256) void scan_partial(
    const int* __restrict__ deg, int* __restrict__ partials)
{
    __shared__ int sm[256];
    int i = blockIdx.x * 256 + threadIdx.x;
    int v = (i <= N_NODES) ? deg[i] : 0;
    sm[threadIdx.x] = v;
    __syncthreads();
    for (int off = 128; off > 0; off >>= 1) {
        if (threadIdx.x < off) sm[threadIdx.x] += sm[threadIdx.x + off];
        __syncthreads();
    }
    if (threadIdx.x == 0) partials[blockIdx.x] = sm[0];
}

__global__ void scan_base(int* __restrict__ partials, int nb)
{
    int base = 0;
    for (int b = 0; b < nb; ++b) {
        int t = partials[b];
        partials[b] = base;
        base += t;
    }
}

__global__ __launch_bounds__(256) void scan_write(
    const int* __restrict__ deg, const int* __restrict__ partials,
    int* __restrict__ offs)
{
    __shared__ int sm[256];
    int i = blockIdx.x * 256 + threadIdx.x;
    int t = threadIdx.x;
    int v = (i <= N_NODES) ? deg[i] : 0;
    sm[t] = v;
    __syncthreads();
    for (int off = 1; off < 256; off <<= 1) {
        int add = (t >= off) ? sm[t - off] : 0;
        __syncthreads();
        sm[t] += add;
        __syncthreads();
    }
    if (i <= N_NODES) offs[i] = partials[blockIdx.x] + sm[t] - v;
}

__global__ __launch_bounds__(256) void csr_fill(
    const int* __restrict__ src, const int* __restrict__ dst,
    const int* __restrict__ offs, int* __restrict__ cursor,
    int* __restrict__ csr_src)
{
    int e = blockIdx.x * 256 + threadIdx.x;
    if (e < N_EDGES) {
        int dn = dst[e];
        int p = atomicAdd(&cursor[dn], 1);
        csr_src[offs[dn] + p] = src[e];
    }
}

// ---------------------------------------------------------------------------
// Gather max-pool over bf16 y. acc=0 realizes relu-before-max + zero-degree->0.
// max of bf16 values is exactly bf16 -> truncating store is exact.
// ---------------------------------------------------------------------------
__global__ __launch_bounds__(64) void pool_max(
    const unsigned short* __restrict__ y, const int* __restrict__ offs,
    const int* __restrict__ csr_src, unsigned short* __restrict__ pool)
{
    int n = blockIdx.x;
    int d = threadIdx.x;                 // lane handles dims {2d, 2d+1}
    int e0 = offs[n], e1 = offs[n + 1];
    float ax = 0.f, ay = 0.f;
    int e = e0;
    for (; e + 1 < e1; e += 2) {
        int s0 = csr_src[e];
        int s1 = csr_src[e + 1];
        ushort2 u0 = *(const ushort2*)&y[s0 * DIN + 2 * d];
        ushort2 u1 = *(const ushort2*)&y[s1 * DIN + 2 * d];
        ax = fmaxf(ax, bf2f(u0.x)); ay = fmaxf(ay, bf2f(u0.y));
        ax = fmaxf(ax, bf2f(u1.x)); ay = fmaxf(ay, bf2f(u1.y));
    }
    if (e < e1) {
        int s0 = csr_src[e];
        ushort2 u0 = *(const ushort2*)&y[s0 * DIN + 2 * d];
        ax = fmaxf(ax, bf2f(u0.x)); ay = fmaxf(ay, bf2f(u0.y));
    }
    ushort2 o;
    o.x = (unsigned short)(__float_as_uint(ax) >> 16);
    o.y = (unsigned short)(__float_as_uint(ay) >> 16);
    *(ushort2*)&pool[n * DIN + 2 * d] = o;
}

extern "C" void kernel_launch(void* const* d_in, const int* in_sizes, int n_in,
                              void* d_out, int out_size, void* d_ws, size_t ws_size,
                              hipStream_t stream) {
    const float* x    = (const float*)d_in[0];
    const int*   esrc = (const int*)d_in[1];
    const int*   edst = (const int*)d_in[2];
    const float* Wp[3], *bp[3], *Ws[3], *Wn[3], *bb[3];
    for (int l = 0; l < 3; ++l) {
        Wp[l] = (const float*)d_in[3 + 5 * l];
        bp[l] = (const float*)d_in[4 + 5 * l];
        Ws[l] = (const float*)d_in[5 + 5 * l];
        Wn[l] = (const float*)d_in[6 + 5 * l];
        bb[l] = (const float*)d_in[7 + 5 * l];
    }

    const int NF = N_NODES * DIN;                    // 6.4M elements
    unsigned short* Y   = (unsigned short*)d_ws;     // bf16 y       (12.8 MB)
    unsigned short* PL  = Y + NF;                    // bf16 pool
    unsigned short* Xh  = PL + NF;                   // x / h2 hi (aliased)
    unsigned short* Xl  = Xh + NF;                   // x / h2 lo
    unsigned short* HAh = Xl + NF;                   // h1 hi
    unsigned short* HAl = HAh + NF;                  // h1 lo
    unsigned short* Wpk = HAl + NF;                  // 9 * 32768 packed weights
    int* deg      = (int*)(Wpk + 9 * 32768);
    int* offs     = deg + (N_NODES + 1);
    int* cursor   = offs + (N_NODES + 1);
    int* partials = cursor + N_NODES;
    int* csr_src  = partials + 256;

    // packed weight plane pointers: matrix i -> hi = Wpk + i*32768, lo = +16384
    auto WH = [&](int i) { return Wpk + i * 32768; };
    auto WL = [&](int i) { return Wpk + i * 32768 + 16384; };
    // order: 0=Wp1 1=Ws1 2=Wn1 3=Wp2 4=Ws2 5=Wn2 6=Wp3 7=Ws3 8=Wn3

    const dim3 blk(256);
    const int edgeBlocks = (N_EDGES + 255) / 256;
    const int scanBlocks = (N_NODES + 1 + 255) / 256;
    const int gemmBlocks = (N_NODES + 63) / 64;      // 782

    // ---- prep: weights + x conversion ----
    WDescs wd;
    wd.d[0] = {Wp[0], 128}; wd.d[1] = {Ws[0], 128}; wd.d[2] = {Wn[0], 128};
    wd.d[3] = {Wp[1], 128}; wd.d[4] = {Ws[1], 128}; wd.d[5] = {Wn[1], 128};
    wd.d[6] = {Wp[2], 128}; wd.d[7] = {Ws[2], 64};  wd.d[8] = {Wn[2], 64};
    convert_weights<<<dim3(64, 9), blk, 0, stream>>>(wd, Wpk);
    convert_x<<<NF / 512, blk, 0, stream>>>(x, Xh, Xl);

    // ---- CSR build ----
    hipMemsetAsync(deg, 0, (2 * (N_NODES + 1) + N_NODES + 256) * sizeof(int), stream);
    edge_histogram<<<edgeBlocks, blk, 0, stream>>>(edst, deg);
    scan_partial<<<scanBlocks, blk, 0, stream>>>(deg, partials);
    scan_base<<<1, 1, 0, stream>>>(partials, scanBlocks);
    scan_write<<<scanBlocks, blk, 0, stream>>>(deg, partials, offs);
    csr_fill<<<edgeBlocks, blk, 0, stream>>>(esrc, edst, offs, cursor, csr_src);

    GSegs s1, s2;

    // ---- Layer 1: A = x (hi/lo), out h1 -> HA ----
    s1.a[0] = Xh; s1.b[0] = WH(0);
    gemm_mfma<8, 1, 0><<<gemmBlocks, blk, 0, stream>>>(s1, bp[0], Y, nullptr, nullptr, N_NODES);
    pool_max<<<N_NODES, 64, 0, stream>>>(Y, offs, csr_src, PL);
    s2.a[0] = Xh; s2.b[0] = WH(1);
    s2.a[1] = Xh; s2.b[1] = WL(1);
    s2.a[2] = Xl; s2.b[2] = WH(1);
    s2.a[3] = PL; s2.b[3] = WH(2);
    gemm_mfma<8, 4, 1><<<gemmBlocks, blk, 0, stream>>>(s2, bb[0], HAh, HAl, nullptr, N_NODES);

    // ---- Layer 2: A = h1 (HA), out h2 -> X planes (x is dead) ----
    s1.a[0] = HAh; s1.b[0] = WH(3);
    gemm_mfma<8, 1, 0><<<gemmBlocks, blk, 0, stream>>>(s1, bp[1], Y, nullptr, nullptr, N_NODES);
    pool_max<<<N_NODES, 64, 0, stream>>>(Y, offs, csr_src, PL);
    s2.a[0] = HAh; s2.b[0] = WH(4);
    s2.a[1] = HAh; s2.b[1] = WL(4);
    s2.a[2] = HAl; s2.b[2] = WH(4);
    s2.a[3] = PL;  s2.b[3] = WH(5);
    gemm_mfma<8, 4, 1><<<gemmBlocks, blk, 0, stream>>>(s2, bb[1], Xh, Xl, nullptr, N_NODES);

    // ---- Layer 3: A = h2 (X planes), out -> d_out (N=64, fp32) ----
    s1.a[0] = Xh; s1.b[0] = WH(6);
    gemm_mfma<8, 1, 0><<<gemmBlocks, blk, 0, stream>>>(s1, bp[2], Y, nullptr, nullptr, N_NODES);
    pool_max<<<N_NODES, 64, 0, stream>>>(Y, offs, csr_src, PL);
    s2.a[0] = Xh; s2.b[0] = WH(7);
    s2.a[1] = Xh; s2.b[1] = WL(7);
    s2.a[2] = Xl; s2.b[2] = WH(7);
    s2.a[3] = PL; s2.b[3] = WH(8);
    gemm_mfma<4, 4, 2><<<gemmBlocks, blk, 0, stream>>>(s2, bb[2], nullptr, nullptr, (float*)d_out, N_NODES);
}

// Round 4
// 446.981 us; speedup vs baseline: 3.1760x; 1.0585x over previous
//
#include <hip/hip_runtime.h>
#include <math.h>

#define N_NODES 50000
#define N_EDGES 800000
#define DIN 128
#define RANGES 8
#define NODES_PER_RANGE 6250   // 50000 / 8

typedef __attribute__((ext_vector_type(8))) short short8;   // 8 bf16
typedef __attribute__((ext_vector_type(4))) float f32x4;    // 4 fp32 acc

// ---------------- bf16 helpers (RNE) ----------------
__device__ __forceinline__ unsigned short f2bf(float f) {
    unsigned int u = __float_as_uint(f);
    return (unsigned short)((u + 0x7FFFu + ((u >> 16) & 1u)) >> 16);
}
__device__ __forceinline__ float bf2f(unsigned short h) {
    return __uint_as_float(((unsigned int)h) << 16);
}

// ---------------------------------------------------------------------------
// MFMA GEMM, 16x16x32 bf16. Block = 256 thr = 4 waves; each wave owns 16 rows
// x N cols. A: row-major bf16 planes straight from global (16B/lane).
// B: pre-packed fragment layout (wave-contiguous 1KB loads, L1-resident).
// Segments realize the fp32 hi/lo split: acc = sum_s A_s @ B_s.
// OMODE 0: out = acc+bias -> bf16 raw (y for pooling)
// OMODE 1: l2norm+relu -> bf16 hi/lo planes (next layer's A)
// OMODE 2: l2norm+relu -> fp32 (final output)
// ---------------------------------------------------------------------------
struct GSegs { const unsigned short* a[4]; const unsigned short* b[4]; };

template <int NTILES, int NSEG, int OMODE>
__global__ __launch_bounds__(256) void gemm_mfma(
    GSegs segs, const float* __restrict__ bias,
    unsigned short* __restrict__ outH, unsigned short* __restrict__ outL,
    float* __restrict__ outF, int M)
{
    const int N = NTILES * 16;
    const int lane = threadIdx.x & 63;
    const int wv = threadIdx.x >> 6;
    const int cl = lane & 15;
    const int quad = lane >> 4;
    const int rowBase = blockIdx.x * 64 + wv * 16;

    f32x4 acc[NTILES];
    #pragma unroll
    for (int t = 0; t < NTILES; ++t) acc[t] = (f32x4){0.f, 0.f, 0.f, 0.f};

    const int aBase = (rowBase + cl) * 128 + quad * 8;
    const int bLane = cl * 32 + quad * 8;

    #pragma unroll
    for (int s = 0; s < NSEG; ++s) {
        const unsigned short* __restrict__ A = segs.a[s];
        const unsigned short* __restrict__ B = segs.b[s];
        #pragma unroll
        for (int c = 0; c < 4; ++c) {
            short8 af = *(const short8*)(A + aBase + c * 32);
            const unsigned short* Bc = B + c * (N * 32) + bLane;
            #pragma unroll
            for (int t = 0; t < NTILES; ++t) {
                short8 bf = *(const short8*)(Bc + t * 512);
                acc[t] = __builtin_amdgcn_mfma_f32_16x16x32_bf16(af, bf, acc[t], 0, 0, 0);
            }
        }
    }

    #pragma unroll
    for (int t = 0; t < NTILES; ++t) {
        float bc = bias[t * 16 + cl];
        #pragma unroll
        for (int g = 0; g < 4; ++g) acc[t][g] += bc;
    }

    const int row0 = rowBase + quad * 4;

    if (OMODE == 0) {
        #pragma unroll
        for (int t = 0; t < NTILES; ++t)
            #pragma unroll
            for (int g = 0; g < 4; ++g) {
                int r = row0 + g;
                if (r < M) outH[r * N + t * 16 + cl] = f2bf(acc[t][g]);
            }
        return;
    }

    // fused row-wise L2 norm: each row lives in 16 lanes of this quad group
    float inv[4];
    #pragma unroll
    for (int g = 0; g < 4; ++g) {
        float s = 0.f;
        #pragma unroll
        for (int t = 0; t < NTILES; ++t) s += acc[t][g] * acc[t][g];
        s += __shfl_xor(s, 1, 64);
        s += __shfl_xor(s, 2, 64);
        s += __shfl_xor(s, 4, 64);
        s += __shfl_xor(s, 8, 64);
        inv[g] = 1.0f / fmaxf(sqrtf(s), 1e-12f);
    }

    #pragma unroll
    for (int t = 0; t < NTILES; ++t)
        #pragma unroll
        for (int g = 0; g < 4; ++g) {
            int r = row0 + g;
            if (r >= M) continue;
            float o = fmaxf(acc[t][g] * inv[g], 0.0f);
            int off = r * N + t * 16 + cl;
            if (OMODE == 1) {
                unsigned short h = f2bf(o);
                outH[off] = h;
                outL[off] = f2bf(o - bf2f(h));
            } else {
                outF[off] = o;
            }
        }
}

// ---------------------------------------------------------------------------
// Weight pre-pack: W[K x N] fp32 -> hi/lo bf16 in fragment layout.
// ---------------------------------------------------------------------------
struct WDesc { const float* W; int N; };
struct WDescs { WDesc d[9]; };

__global__ __launch_bounds__(256) void convert_weights(WDescs wd, unsigned short* base)
{
    int mi = blockIdx.y;
    int id = blockIdx.x * 256 + threadIdx.x;
    const float* W = wd.d[mi].W;
    int N = wd.d[mi].N;
    if (id >= 128 * N) return;
    int c = id / (N * 32);
    int n = (id - c * N * 32) >> 5;
    int k = c * 32 + (id & 31);
    float v = W[k * N + n];
    unsigned short h = f2bf(v);
    unsigned short* hi = base + mi * 32768;
    hi[id] = h;
    hi[16384 + id] = f2bf(v - bf2f(h));
}

__global__ __launch_bounds__(256) void convert_x(
    const float* __restrict__ x, unsigned short* __restrict__ xh,
    unsigned short* __restrict__ xl)
{
    int i = blockIdx.x * 256 + threadIdx.x;
    float2 v = ((const float2*)x)[i];
    ushort2 h, l;
    h.x = f2bf(v.x); l.x = f2bf(v.x - bf2f(h.x));
    h.y = f2bf(v.y); l.y = f2bf(v.y - bf2f(h.y));
    ((ushort2*)xh)[i] = h;
    ((ushort2*)xl)[i] = l;
}

// ---------------------------------------------------------------------------
// CSR build, pass 1: histogram + per-edge rank in one pass.
// rank[e] = position of edge e within its dst node's segment.
// ---------------------------------------------------------------------------
__global__ __launch_bounds__(256) void hist_rank(
    const int* __restrict__ dst, int* __restrict__ deg, int* __restrict__ rank)
{
    int e = blockIdx.x * 256 + threadIdx.x;   // grid exact (800000/256)
    rank[e] = atomicAdd(&deg[dst[e]], 1);
}

// Pass 2a: per-block partial sums of deg (50001 entries, 196 blocks).
__global__ __launch_bounds__(256) void scan_partial(
    const int* __restrict__ deg, int* __restrict__ partials)
{
    __shared__ int sm[256];
    int i = blockIdx.x * 256 + threadIdx.x;
    int v = (i <= N_NODES) ? deg[i] : 0;
    sm[threadIdx.x] = v;
    __syncthreads();
    for (int off = 128; off > 0; off >>= 1) {
        if (threadIdx.x < off) sm[threadIdx.x] += sm[threadIdx.x + off];
        __syncthreads();
    }
    if (threadIdx.x == 0) partials[blockIdx.x] = sm[0];
}

// Pass 2b: each block scans all partials in LDS (nb <= 256) for its base,
// plus intra-block Hillis-Steele exclusive scan of its deg chunk -> offs.
__global__ __launch_bounds__(256) void scan_write(
    const int* __restrict__ deg, const int* __restrict__ partials,
    int* __restrict__ offs, int nb)
{
    __shared__ int sp[256];
    __shared__ int sm[256];
    int t = threadIdx.x;
    int i = blockIdx.x * 256 + t;
    sp[t] = (t < nb) ? partials[t] : 0;
    int v = (i <= N_NODES) ? deg[i] : 0;
    sm[t] = v;
    __syncthreads();
    for (int off = 1; off < 256; off <<= 1) {
        int a1 = (t >= off) ? sp[t - off] : 0;
        int a2 = (t >= off) ? sm[t - off] : 0;
        __syncthreads();
        sp[t] += a1;
        sm[t] += a2;
        __syncthreads();
    }
    int base = (blockIdx.x > 0) ? sp[blockIdx.x - 1] : 0;
    if (i <= N_NODES) offs[i] = base + sm[t] - v;
}

// ---------------------------------------------------------------------------
// CSR build, pass 3: XCD-partitioned scatter (no atomics).
// Grid = RANGES x edgeChunks; range = blockIdx & 7 so (round-robin block->XCD)
// each dst range's csr lines are written by one XCD only -> no line ping-pong.
// csr16 is ushort (N_NODES < 65536): half the scatter bytes.
// ---------------------------------------------------------------------------
__global__ __launch_bounds__(256) void csr_fill2(
    const int* __restrict__ src, const int* __restrict__ dst,
    const int* __restrict__ rank, const int* __restrict__ offs,
    unsigned short* __restrict__ csr16)
{
    int range = blockIdx.x & (RANGES - 1);
    int e = (blockIdx.x >> 3) * 256 + threadIdx.x;   // grid exact per range
    int d = dst[e];
    if ((unsigned)(d - range * NODES_PER_RANGE) >= (unsigned)NODES_PER_RANGE) return;
    csr16[offs[d] + rank[e]] = (unsigned short)src[e];
}

// ---------------------------------------------------------------------------
// Gather max-pool over bf16 y. 4 waves/block, one node per wave.
// acc=0 realizes relu-before-max + zero-degree->0; bf16 max is exact.
// ---------------------------------------------------------------------------
__global__ __launch_bounds__(256) void pool_max(
    const unsigned short* __restrict__ y, const int* __restrict__ offs,
    const unsigned short* __restrict__ csr16, unsigned short* __restrict__ pool)
{
    int wv = threadIdx.x >> 6;
    int d = threadIdx.x & 63;            // lane handles dims {2d, 2d+1}
    int n = blockIdx.x * 4 + wv;
    int e0 = offs[n], e1 = offs[n + 1];
    float ax = 0.f, ay = 0.f;
    int e = e0;
    for (; e + 1 < e1; e += 2) {
        int s0 = csr16[e];
        int s1 = csr16[e + 1];
        ushort2 u0 = *(const ushort2*)&y[s0 * DIN + 2 * d];
        ushort2 u1 = *(const ushort2*)&y[s1 * DIN + 2 * d];
        ax = fmaxf(ax, bf2f(u0.x)); ay = fmaxf(ay, bf2f(u0.y));
        ax = fmaxf(ax, bf2f(u1.x)); ay = fmaxf(ay, bf2f(u1.y));
    }
    if (e < e1) {
        int s0 = csr16[e];
        ushort2 u0 = *(const ushort2*)&y[s0 * DIN + 2 * d];
        ax = fmaxf(ax, bf2f(u0.x)); ay = fmaxf(ay, bf2f(u0.y));
    }
    ushort2 o;
    o.x = (unsigned short)(__float_as_uint(ax) >> 16);
    o.y = (unsigned short)(__float_as_uint(ay) >> 16);
    *(ushort2*)&pool[n * DIN + 2 * d] = o;
}

extern "C" void kernel_launch(void* const* d_in, const int* in_sizes, int n_in,
                              void* d_out, int out_size, void* d_ws, size_t ws_size,
                              hipStream_t stream) {
    const float* x    = (const float*)d_in[0];
    const int*   esrc = (const int*)d_in[1];
    const int*   edst = (const int*)d_in[2];
    const float* Wp[3], *bp[3], *Ws[3], *Wn[3], *bb[3];
    for (int l = 0; l < 3; ++l) {
        Wp[l] = (const float*)d_in[3 + 5 * l];
        bp[l] = (const float*)d_in[4 + 5 * l];
        Ws[l] = (const float*)d_in[5 + 5 * l];
        Wn[l] = (const float*)d_in[6 + 5 * l];
        bb[l] = (const float*)d_in[7 + 5 * l];
    }

    const int NF = N_NODES * DIN;                    // 6.4M elements
    unsigned short* Y   = (unsigned short*)d_ws;     // bf16 y       (12.8 MB)
    unsigned short* PL  = Y + NF;                    // bf16 pool
    unsigned short* Xh  = PL + NF;                   // x / h2 hi (aliased)
    unsigned short* Xl  = Xh + NF;                   // x / h2 lo
    unsigned short* HAh = Xl + NF;                   // h1 hi
    unsigned short* HAl = HAh + NF;                  // h1 lo
    unsigned short* Wpk = HAl + NF;                  // 9 * 32768 packed weights
    int* deg      = (int*)(Wpk + 9 * 32768);         // 50001
    int* offs     = deg + (N_NODES + 1);             // 50001
    int* partials = offs + (N_NODES + 1);            // 256
    int* rank     = partials + 256;                  // 800000
    unsigned short* csr16 = (unsigned short*)(rank + N_EDGES); // 800000 ushort

    auto WH = [&](int i) { return Wpk + i * 32768; };
    auto WL = [&](int i) { return Wpk + i * 32768 + 16384; };
    // order: 0=Wp1 1=Ws1 2=Wn1 3=Wp2 4=Ws2 5=Wn2 6=Wp3 7=Ws3 8=Wn3

    const dim3 blk(256);
    const int edgeBlocks = N_EDGES / 256;                 // 3125, exact
    const int scanBlocks = (N_NODES + 1 + 255) / 256;     // 196
    const int gemmBlocks = (N_NODES + 63) / 64;           // 782

    // ---- prep: weights + x conversion ----
    WDescs wd;
    wd.d[0] = {Wp[0], 128}; wd.d[1] = {Ws[0], 128}; wd.d[2] = {Wn[0], 128};
    wd.d[3] = {Wp[1], 128}; wd.d[4] = {Ws[1], 128}; wd.d[5] = {Wn[1], 128};
    wd.d[6] = {Wp[2], 128}; wd.d[7] = {Ws[2], 64};  wd.d[8] = {Wn[2], 64};
    convert_weights<<<dim3(64, 9), blk, 0, stream>>>(wd, Wpk);
    convert_x<<<NF / 512, blk, 0, stream>>>(x, Xh, Xl);

    // ---- CSR build ----
    hipMemsetAsync(deg, 0, (N_NODES + 1) * sizeof(int), stream);
    hist_rank<<<edgeBlocks, blk, 0, stream>>>(edst, deg, rank);
    scan_partial<<<scanBlocks, blk, 0, stream>>>(deg, partials);
    scan_write<<<scanBlocks, blk, 0, stream>>>(deg, partials, offs, scanBlocks);
    csr_fill2<<<edgeBlocks * RANGES, blk, 0, stream>>>(esrc, edst, rank, offs, csr16);

    GSegs s1, s2;

    // ---- Layer 1: A = x (hi/lo), out h1 -> HA ----
    s1.a[0] = Xh; s1.b[0] = WH(0);
    gemm_mfma<8, 1, 0><<<gemmBlocks, blk, 0, stream>>>(s1, bp[0], Y, nullptr, nullptr, N_NODES);
    pool_max<<<N_NODES / 4, blk, 0, stream>>>(Y, offs, csr16, PL);
    s2.a[0] = Xh; s2.b[0] = WH(1);
    s2.a[1] = Xl; s2.b[1] = WH(1);
    s2.a[2] = PL; s2.b[2] = WH(2);
    gemm_mfma<8, 3, 1><<<gemmBlocks, blk, 0, stream>>>(s2, bb[0], HAh, HAl, nullptr, N_NODES);

    // ---- Layer 2: A = h1 (HA), out h2 -> X planes (x is dead) ----
    s1.a[0] = HAh; s1.b[0] = WH(3);
    gemm_mfma<8, 1, 0><<<gemmBlocks, blk, 0, stream>>>(s1, bp[1], Y, nullptr, nullptr, N_NODES);
    pool_max<<<N_NODES / 4, blk, 0, stream>>>(Y, offs, csr16, PL);
    s2.a[0] = HAh; s2.b[0] = WH(4);
    s2.a[1] = HAl; s2.b[1] = WH(4);
    s2.a[2] = PL;  s2.b[2] = WH(5);
    gemm_mfma<8, 3, 1><<<gemmBlocks, blk, 0, stream>>>(s2, bb[1], Xh, Xl, nullptr, N_NODES);

    // ---- Layer 3: A = h2 (X planes), out -> d_out (N=64, fp32) ----
    s1.a[0] = Xh; s1.b[0] = WH(6);
    gemm_mfma<8, 1, 0><<<gemmBlocks, blk, 0, stream>>>(s1, bp[2], Y, nullptr, nullptr, N_NODES);
    pool_max<<<N_NODES / 4, blk, 0, stream>>>(Y, offs, csr16, PL);
    s2.a[0] = Xh; s2.b[0] = WH(7);
    s2.a[1] = Xl; s2.b[1] = WH(7);
    s2.a[2] = PL; s2.b[2] = WH(8);
    gemm_mfma<4, 3, 2><<<gemmBlocks, blk, 0, stream>>>(s2, bb[2], nullptr, nullptr, (float*)d_out, N_NODES);
}